// Round 5
// baseline (1267.641 us; speedup 1.0000x reference)
//
#include <hip/hip_runtime.h>
#include <math.h>

constexpr int N_NODES = 4096;
constexpr int E_EDGES = 131072;
constexpr int IND     = 1024;
constexpr int HID     = 512;
constexpr int OUTD    = 128;
constexpr int PEH     = 64;
constexpr int KHOP    = 10;
constexpr int NPE     = N_NODES * PEH;    // 262144
constexpr int NM      = N_NODES * OUTD;   // 524288
constexpr int NCHUNK  = 32;               // corr column chunks (128 cols each)

__constant__ float d_coeff[11] = {
    1.f/1024.f, 10.f/1024.f, 45.f/1024.f, 120.f/1024.f, 210.f/1024.f,
    252.f/1024.f, 210.f/1024.f, 120.f/1024.f, 45.f/1024.f, 10.f/1024.f, 1.f/1024.f};

// beta[j][m]: (1-t)^j (1+t)^(10-j) = sum_m beta[j][m] t^m
__constant__ float d_beta[11][11] = {
    {1,  10, 45, 120, 210, 252, 210, 120, 45, 10, 1},
    {1,   8, 27,  48,  42,   0, -42, -48, -27, -8, -1},
    {1,   6, 13,   8, -14, -28, -14,   8,  13,  6,  1},
    {1,   4,  3,  -8, -14,   0,  14,   8,  -3, -4, -1},
    {1,   2, -3,  -8,   2,  12,   2,  -8,  -3,  2,  1},
    {1,   0, -5,   0,  10,   0, -10,   0,   5,  0, -1},
    {1,  -2, -3,   8,   2, -12,   2,   8,  -3, -2,  1},
    {1,  -4,  3,   8, -14,   0,  14,  -8,  -3,  4, -1},
    {1,  -6, 13,  -8, -14,  28, -14,  -8,  13, -6,  1},
    {1,  -8, 27, -48,  42,   0, -42,  48, -27,  8, -1},
    {1, -10, 45, -120, 210, -252, 210, -120, 45, -10, 1}};

typedef __attribute__((ext_vector_type(8))) short bf16x8;
typedef __attribute__((ext_vector_type(4))) float f32x4;

__device__ __forceinline__ void split_bf16(float x, short& h, short& l) {
    unsigned bx = __float_as_uint(x);
    h = (short)(bx >> 16);
    float hf = __uint_as_float(bx & 0xffff0000u);
    l = (short)(__float_as_uint(x - hf) >> 16);
}

// element index into a 64x64 ushort LDS tile, XOR-swizzled at 16B granularity
__device__ __forceinline__ int swz(int row, int col) {
    return row * 64 + (col ^ ((row & 7) << 3));
}

// ---------------- graph prep ----------------
__global__ void k_degrees(const int* __restrict__ src, const int* __restrict__ dst,
                          int* outdeg, int* indeg) {
    int e = blockIdx.x * blockDim.x + threadIdx.x;
    if (e < E_EDGES) {
        atomicAdd(&outdeg[src[e]], 1);
        atomicAdd(&indeg[dst[e]], 1);
    }
}

__global__ void k_invs(const int* __restrict__ outdeg, const int* __restrict__ indeg,
                       float* dinv, float* d2) {
    int i = blockIdx.x * blockDim.x + threadIdx.x;
    if (i < N_NODES) {
        int od = outdeg[i];
        dinv[i] = od > 0 ? 1.0f / sqrtf((float)od) : 0.0f;
        d2[i]   = 1.0f / sqrtf((float)indeg[i] + 1.0f);
    }
}

__global__ void k_scan(const int* __restrict__ cnt, int* __restrict__ rp) {
    int lane = threadIdx.x;  // 0..63
    int base = lane * 64;
    int sum = 0;
    for (int j = 0; j < 64; ++j) sum += cnt[base + j];
    int incl = sum;
    for (int off = 1; off < 64; off <<= 1) {
        int nv = __shfl_up(incl, off);
        if (lane >= off) incl += nv;
    }
    int run = incl - sum;
    for (int j = 0; j < 64; ++j) { rp[base + j] = run; run += cnt[base + j]; }
    if (lane == 63) rp[N_NODES] = run;
}

__global__ void k_scatter(const int* __restrict__ src, const int* __restrict__ dst,
                          const int* __restrict__ rp, int* __restrict__ fill,
                          const float* __restrict__ dinv, const float* __restrict__ d2,
                          int* __restrict__ col, float* __restrict__ wl,
                          float* __restrict__ wg) {
    int e = blockIdx.x * blockDim.x + threadIdx.x;
    if (e < E_EDGES) {
        int s = src[e], d = dst[e];
        int pos = rp[d] + atomicAdd(&fill[d], 1);
        col[pos] = s;
        wl[pos]  = dinv[s] * dinv[d];
        wg[pos]  = d2[s] * d2[d];
    }
}

// ---------------- split helpers ----------------
__global__ void k_split_rm(const float* __restrict__ in, ushort* __restrict__ oh,
                           ushort* __restrict__ ol, int total8) {
    int i = blockIdx.x * blockDim.x + threadIdx.x;
    if (i >= total8) return;
    float4 f0 = *(const float4*)&in[(size_t)i * 8];
    float4 f1 = *(const float4*)&in[(size_t)i * 8 + 4];
    float v[8] = {f0.x, f0.y, f0.z, f0.w, f1.x, f1.y, f1.z, f1.w};
    bf16x8 h, l;
#pragma unroll
    for (int j = 0; j < 8; ++j) {
        short hh, ll;
        split_bf16(v[j], hh, ll);
        h[j] = hh; l[j] = ll;
    }
    *(bf16x8*)&oh[(size_t)i * 8] = h;
    *(bf16x8*)&ol[(size_t)i * 8] = l;
}

// f32 [R][C] -> transposed hi/lo bf16 [C][R]
__global__ __launch_bounds__(256) void k_splitT(const float* __restrict__ in,
                                                ushort* __restrict__ th,
                                                ushort* __restrict__ tl,
                                                int R, int C) {
    __shared__ float tile[64][65];
    int tid = threadIdx.x;
    int r0 = blockIdx.x * 64, c0 = blockIdx.y * 64;
    int row = tid >> 2, cq = (tid & 3) * 16;
#pragma unroll
    for (int q = 0; q < 4; ++q) {
        float4 f = *(const float4*)&in[(size_t)(r0 + row) * C + c0 + cq + q * 4];
        tile[row][cq + q * 4 + 0] = f.x;
        tile[row][cq + q * 4 + 1] = f.y;
        tile[row][cq + q * 4 + 2] = f.z;
        tile[row][cq + q * 4 + 3] = f.w;
    }
    __syncthreads();
    int d = tid & 63, q = tid >> 6;
    bf16x8 h0, h1, l0, l1;
#pragma unroll
    for (int c = 0; c < 8; ++c) {
        short hh, ll;
        split_bf16(tile[q * 16 + c][d], hh, ll);
        h0[c] = hh; l0[c] = ll;
    }
#pragma unroll
    for (int c = 0; c < 8; ++c) {
        short hh, ll;
        split_bf16(tile[q * 16 + 8 + c][d], hh, ll);
        h1[c] = hh; l1[c] = ll;
    }
    size_t ob = (size_t)(c0 + d) * R + r0 + q * 16;
    *(bf16x8*)&th[ob] = h0;
    *(bf16x8*)&th[ob + 8] = h1;
    *(bf16x8*)&tl[ob] = l0;
    *(bf16x8*)&tl[ob + 8] = l1;
}

// ------------- MFMA GEMM, K-split (z): partials, hi/lo 3-pass ----------------
template <int KD, int KCH>
__global__ __launch_bounds__(256) void k_xgemm_z(const ushort* __restrict__ ah,
                                                 const ushort* __restrict__ al,
                                                 const ushort* __restrict__ bth,
                                                 const ushort* __restrict__ btl,
                                                 float* __restrict__ pout, int NC) {
    int tid = threadIdx.x;
    int w = tid >> 6, l = tid & 63, lm = l & 15, lq = l >> 4;
    int r0 = blockIdx.x * 64, n0 = blockIdx.y * 64;
    int kb = blockIdx.z * KCH;
    f32x4 acc[4];
#pragma unroll
    for (int n = 0; n < 4; ++n) acc[n] = (f32x4){0.f, 0.f, 0.f, 0.f};
    const ushort* aH = ah + (size_t)(r0 + w * 16 + lm) * KD + kb + lq * 8;
    const ushort* aL = al + (size_t)(r0 + w * 16 + lm) * KD + kb + lq * 8;
    for (int k0 = 0; k0 < KCH; k0 += 64) {
        bf16x8 Ah0 = *(const bf16x8*)&aH[k0];
        bf16x8 Ah1 = *(const bf16x8*)&aH[k0 + 32];
        bf16x8 Al0 = *(const bf16x8*)&aL[k0];
        bf16x8 Al1 = *(const bf16x8*)&aL[k0 + 32];
#pragma unroll
        for (int n = 0; n < 4; ++n) {
            const ushort* bH = bth + (size_t)(n0 + n * 16 + lm) * KD + kb + k0 + lq * 8;
            const ushort* bL = btl + (size_t)(n0 + n * 16 + lm) * KD + kb + k0 + lq * 8;
            bf16x8 Bh0 = *(const bf16x8*)&bH[0];
            bf16x8 Bh1 = *(const bf16x8*)&bH[32];
            bf16x8 Bl0 = *(const bf16x8*)&bL[0];
            bf16x8 Bl1 = *(const bf16x8*)&bL[32];
            acc[n] = __builtin_amdgcn_mfma_f32_16x16x32_bf16(Ah0, Bh0, acc[n], 0, 0, 0);
            acc[n] = __builtin_amdgcn_mfma_f32_16x16x32_bf16(Ah1, Bh1, acc[n], 0, 0, 0);
            acc[n] = __builtin_amdgcn_mfma_f32_16x16x32_bf16(Ah0, Bl0, acc[n], 0, 0, 0);
            acc[n] = __builtin_amdgcn_mfma_f32_16x16x32_bf16(Ah1, Bl1, acc[n], 0, 0, 0);
            acc[n] = __builtin_amdgcn_mfma_f32_16x16x32_bf16(Al0, Bh0, acc[n], 0, 0, 0);
            acc[n] = __builtin_amdgcn_mfma_f32_16x16x32_bf16(Al1, Bh1, acc[n], 0, 0, 0);
        }
    }
    float* dst = pout + (size_t)blockIdx.z * N_NODES * NC;
#pragma unroll
    for (int n = 0; n < 4; ++n) {
#pragma unroll
        for (int r = 0; r < 4; ++r) {
            dst[(size_t)(r0 + w * 16 + lq * 4 + r) * NC + n0 + n * 16 + lm] = acc[n][r];
        }
    }
}

// reduce z=4 partials + bias (+relu) (+split to hi/lo bf16)
template <bool RELU, bool SPLIT>
__global__ void k_finz(const float* __restrict__ pin, const float* __restrict__ bias,
                       float* __restrict__ outf, ushort* __restrict__ oh,
                       ushort* __restrict__ ol, int NC, int total) {
    int i = (blockIdx.x * blockDim.x + threadIdx.x) * 4;
    if (i >= total) return;
    float4 v = *(const float4*)&bias[i & (NC - 1)];
#pragma unroll
    for (int z = 0; z < 4; ++z) {
        float4 p = *(const float4*)&pin[(size_t)z * total + i];
        v.x += p.x; v.y += p.y; v.z += p.z; v.w += p.w;
    }
    if (RELU) {
        v.x = fmaxf(v.x, 0.f); v.y = fmaxf(v.y, 0.f);
        v.z = fmaxf(v.z, 0.f); v.w = fmaxf(v.w, 0.f);
    }
    if (SPLIT) {
        short h0, l0, h1, l1, h2, l2, h3, l3;
        split_bf16(v.x, h0, l0); split_bf16(v.y, h1, l1);
        split_bf16(v.z, h2, l2); split_bf16(v.w, h3, l3);
        *(ushort4*)&oh[i] = make_ushort4((ushort)h0, (ushort)h1, (ushort)h2, (ushort)h3);
        *(ushort4*)&ol[i] = make_ushort4((ushort)l0, (ushort)l1, (ushort)l2, (ushort)l3);
    } else {
        *(float4*)&outf[i] = v;
    }
}

// -------- PE encoder: pe = tanh(pos_enc @ pe_w + pe_b), fused gamma[0] --------
__global__ __launch_bounds__(256) void k_pe0(const float* __restrict__ pos_enc,
                                             const float* __restrict__ pw,
                                             const float* __restrict__ pb,
                                             float* __restrict__ pe,
                                             float* __restrict__ raw,
                                             ushort* __restrict__ pth,
                                             ushort* __restrict__ ptl,
                                             const float* __restrict__ gw,
                                             const float* __restrict__ gb,
                                             const float* __restrict__ temp,
                                             float* __restrict__ gamma) {
    __shared__ float tile[64][65];
    int tid = threadIdx.x, w = tid >> 6, l = tid & 63;
    int nloc = w * 16 + (l >> 2);
    int n = blockIdx.x * 64 + nloc;
    int f0 = (l & 3) * 16;
    float v[16];
#pragma unroll
    for (int f = 0; f < 16; ++f) v[f] = pb[f0 + f];
    for (int k0 = 0; k0 < 128; k0 += 4) {
        float4 pv = *(const float4*)&pos_enc[(size_t)n * 128 + k0];
        float pa[4] = {pv.x, pv.y, pv.z, pv.w};
#pragma unroll
        for (int kk = 0; kk < 4; ++kk) {
            const float* wr = &pw[(size_t)(k0 + kk) * 64 + f0];
            float4 w0 = *(const float4*)&wr[0];
            float4 w1 = *(const float4*)&wr[4];
            float4 w2 = *(const float4*)&wr[8];
            float4 w3 = *(const float4*)&wr[12];
            float wv[16] = {w0.x, w0.y, w0.z, w0.w, w1.x, w1.y, w1.z, w1.w,
                            w2.x, w2.y, w2.z, w2.w, w3.x, w3.y, w3.z, w3.w};
#pragma unroll
            for (int f = 0; f < 16; ++f) v[f] = fmaf(pa[kk], wv[f], v[f]);
        }
    }
#pragma unroll
    for (int f = 0; f < 16; ++f) v[f] = tanhf(v[f]);
#pragma unroll
    for (int q = 0; q < 4; ++q) {
        float4 fv = make_float4(v[q * 4], v[q * 4 + 1], v[q * 4 + 2], v[q * 4 + 3]);
        *(float4*)&pe[(size_t)n * 64 + f0 + q * 4] = fv;
        *(float4*)&raw[(size_t)n * 64 + f0 + q * 4] = fv;
    }
    // gamma[0]: dot(v, gate_w[0]) over 64 dims (4 lanes per node)
    float g = 0.f;
#pragma unroll
    for (int f = 0; f < 16; ++f) g = fmaf(v[f], gw[f0 + f], g);
    g += __shfl_xor(g, 1);
    g += __shfl_xor(g, 2);
    if ((l & 3) == 0) {
        float T = temp[0];
        T = T > 0.f ? T : 0.f;
        gamma[n] = T / (1.f + expf(-(g + gb[0])));
    }
#pragma unroll
    for (int f = 0; f < 16; ++f) tile[nloc][f0 + f] = v[f];
    __syncthreads();
    int d = l, q = w;
    bf16x8 h0, h1, l0, l1;
#pragma unroll
    for (int c = 0; c < 8; ++c) {
        short hh, ll;
        split_bf16(tile[q * 16 + c][d], hh, ll);
        h0[c] = hh; l0[c] = ll;
    }
#pragma unroll
    for (int c = 0; c < 8; ++c) {
        short hh, ll;
        split_bf16(tile[q * 16 + 8 + c][d], hh, ll);
        h1[c] = hh; l1[c] = ll;
    }
    size_t ob = (size_t)d * N_NODES + blockIdx.x * 64 + q * 16;
    *(bf16x8*)&pth[ob] = h0;
    *(bf16x8*)&pth[ob + 8] = h1;
    *(bf16x8*)&ptl[ob] = l0;
    *(bf16x8*)&ptl[ob + 8] = l1;
}

// ---------------- c = pe @ cor_w + cor_b -> split bf16 ----------------
__global__ void k_cmat(const float* __restrict__ pe, const float* __restrict__ cw,
                       const float* __restrict__ cb, ushort* __restrict__ ch,
                       ushort* __restrict__ cl) {
    int t = threadIdx.x;
    int r = blockIdx.x * 4 + threadIdx.y;
    float acc = cb[t];
    for (int k = 0; k < PEH; ++k)
        acc = fmaf(pe[(size_t)r * PEH + k], cw[k * PEH + t], acc);
    short hh, ll;
    split_bf16(acc, hh, ll);
    ch[(size_t)r * PEH + t] = (ushort)hh;
    cl[(size_t)r * PEH + t] = (ushort)ll;
}

// ======== corr4: sigmoid(c c^T) @ pe partials; high-TLP, low-VGPR =============
// grid (64 row-tiles, 32 chunks of 128 cols); 256 thr; per-wave 16-row strip.
__global__ __launch_bounds__(256) void k_corr4(const ushort* __restrict__ ch,
                                               const ushort* __restrict__ cl,
                                               const ushort* __restrict__ pth,
                                               const ushort* __restrict__ ptl,
                                               float* __restrict__ part) {
    __shared__ __align__(16) ushort Sh[4096];
    __shared__ __align__(16) ushort Sl[4096];
    int tid = threadIdx.x, w = tid >> 6, l = tid & 63;
    int lm = l & 15, lq = l >> 4, wrow = w * 16;
    int r0 = blockIdx.x * 64;
    int chunk = blockIdx.y;  // 0..31

    // A fragments (c rows r0+wrow+lm, K=64) — loop-invariant
    const ushort* aH = ch + (size_t)(r0 + wrow + lm) * 64 + lq * 8;
    const ushort* aL = cl + (size_t)(r0 + wrow + lm) * 64 + lq * 8;
    bf16x8 cAh0 = *(const bf16x8*)&aH[0];
    bf16x8 cAh1 = *(const bf16x8*)&aH[32];
    bf16x8 cAl0 = *(const bf16x8*)&aL[0];
    bf16x8 cAl1 = *(const bf16x8*)&aL[32];

    f32x4 pacc[4];
#pragma unroll
    for (int n = 0; n < 4; ++n) pacc[n] = (f32x4){0.f, 0.f, 0.f, 0.f};

#pragma unroll
    for (int t = 0; t < 2; ++t) {
        int c0 = chunk * 128 + t * 64;
        // GEMM1 per n: load B frags, 6 MFMAs, sigmoid+split+store S strip.
        // sacc finalized per-n => short live range; S strip is wave-private.
#pragma unroll
        for (int n = 0; n < 4; ++n) {
            const ushort* bH = ch + (size_t)(c0 + n * 16 + lm) * 64 + lq * 8;
            const ushort* bL = cl + (size_t)(c0 + n * 16 + lm) * 64 + lq * 8;
            bf16x8 Bh0 = *(const bf16x8*)&bH[0];
            bf16x8 Bh1 = *(const bf16x8*)&bH[32];
            bf16x8 Bl0 = *(const bf16x8*)&bL[0];
            bf16x8 Bl1 = *(const bf16x8*)&bL[32];
            f32x4 sacc = (f32x4){0.f, 0.f, 0.f, 0.f};
            sacc = __builtin_amdgcn_mfma_f32_16x16x32_bf16(cAh0, Bh0, sacc, 0, 0, 0);
            sacc = __builtin_amdgcn_mfma_f32_16x16x32_bf16(cAh1, Bh1, sacc, 0, 0, 0);
            sacc = __builtin_amdgcn_mfma_f32_16x16x32_bf16(cAh0, Bl0, sacc, 0, 0, 0);
            sacc = __builtin_amdgcn_mfma_f32_16x16x32_bf16(cAh1, Bl1, sacc, 0, 0, 0);
            sacc = __builtin_amdgcn_mfma_f32_16x16x32_bf16(cAl0, Bh0, sacc, 0, 0, 0);
            sacc = __builtin_amdgcn_mfma_f32_16x16x32_bf16(cAl1, Bh1, sacc, 0, 0, 0);
#pragma unroll
            for (int r = 0; r < 4; ++r) {
                float sg = 1.0f / (1.0f + __expf(-sacc[r]));
                short hh, ll;
                split_bf16(sg, hh, ll);
                int iw = swz(wrow + lq * 4 + r, n * 16 + lm);
                Sh[iw] = (ushort)hh;
                Sl[iw] = (ushort)ll;
            }
        }
        // GEMM2: P += sig(S) @ pe; A from wave-private LDS strip
        bf16x8 sAh0 = *(const bf16x8*)&Sh[swz(wrow + lm, lq * 8)];
        bf16x8 sAh1 = *(const bf16x8*)&Sh[swz(wrow + lm, 32 + lq * 8)];
        bf16x8 sAl0 = *(const bf16x8*)&Sl[swz(wrow + lm, lq * 8)];
        bf16x8 sAl1 = *(const bf16x8*)&Sl[swz(wrow + lm, 32 + lq * 8)];
#pragma unroll
        for (int n = 0; n < 4; ++n) {
            const ushort* bH = pth + (size_t)(n * 16 + lm) * N_NODES + c0 + lq * 8;
            const ushort* bL = ptl + (size_t)(n * 16 + lm) * N_NODES + c0 + lq * 8;
            bf16x8 Ph0 = *(const bf16x8*)&bH[0];
            bf16x8 Ph1 = *(const bf16x8*)&bH[32];
            bf16x8 Pl0 = *(const bf16x8*)&bL[0];
            bf16x8 Pl1 = *(const bf16x8*)&bL[32];
            pacc[n] = __builtin_amdgcn_mfma_f32_16x16x32_bf16(sAh0, Ph0, pacc[n], 0, 0, 0);
            pacc[n] = __builtin_amdgcn_mfma_f32_16x16x32_bf16(sAh1, Ph1, pacc[n], 0, 0, 0);
            pacc[n] = __builtin_amdgcn_mfma_f32_16x16x32_bf16(sAh0, Pl0, pacc[n], 0, 0, 0);
            pacc[n] = __builtin_amdgcn_mfma_f32_16x16x32_bf16(sAh1, Pl1, pacc[n], 0, 0, 0);
            pacc[n] = __builtin_amdgcn_mfma_f32_16x16x32_bf16(sAl0, Ph0, pacc[n], 0, 0, 0);
            pacc[n] = __builtin_amdgcn_mfma_f32_16x16x32_bf16(sAl1, Ph1, pacc[n], 0, 0, 0);
        }
    }
    float* dst = part + (size_t)chunk * NPE;
#pragma unroll
    for (int n = 0; n < 4; ++n) {
#pragma unroll
        for (int r = 0; r < 4; ++r) {
            dst[(size_t)(r0 + wrow + lq * 4 + r) * PEH + n * 16 + lm] = pacc[n][r];
        }
    }
}

// -------- reduce corr partials: 2-way split over grid.y (16 slices each) ------
__global__ void k_csum(const float* __restrict__ corrp, float* __restrict__ corrsum) {
    int i = (blockIdx.x * blockDim.x + threadIdx.x) * 4;
    int half = blockIdx.y;
    const float* base = corrp + (size_t)half * 16 * NPE;
    float4 s = make_float4(0.f, 0.f, 0.f, 0.f);
#pragma unroll
    for (int p = 0; p < 16; ++p) {
        float4 v = *(const float4*)&base[(size_t)p * NPE + i];
        s.x += v.x; s.y += v.y; s.z += v.z; s.w += v.w;
    }
    *(float4*)&corrsum[(size_t)half * NPE + i] = s;
}

// ---------------- ahat (CSR SpMM width 64 + diag) ----------------
__global__ void k_ahat(const float* __restrict__ pe, float* __restrict__ tpo,
                       const int* __restrict__ rp, const int* __restrict__ col,
                       const float* __restrict__ wg, const float* __restrict__ d2) {
    __shared__ int sc[64];
    __shared__ float sw[64];
    int r = blockIdx.x, t = threadIdx.x;
    int e0 = rp[r], e1 = rp[r + 1];
    float dd = d2[r];
    float acc = dd * dd * pe[(size_t)r * PEH + t];
    for (int ch = e0; ch < e1; ch += 64) {
        int n = min(64, e1 - ch);
        __syncthreads();
        if (t < n) { sc[t] = col[ch + t]; sw[t] = wg[ch + t]; }
        __syncthreads();
        for (int q = 0; q < n; ++q)
            acc = fmaf(sw[q], pe[(size_t)sc[q] * PEH + t], acc);
    }
    tpo[(size_t)r * PEH + t] = acc;
}

// ---------------- pe update (block=64 nodes): pe, gamma, peT split ------------
__global__ __launch_bounds__(256) void k_update(const float* __restrict__ tpo,
                                                const float* __restrict__ corrsum,
                                                const float* __restrict__ raw,
                                                float* __restrict__ pe,
                                                const float* __restrict__ gw,
                                                const float* __restrict__ gb,
                                                const float* __restrict__ temp,
                                                float* __restrict__ gamma,
                                                ushort* __restrict__ pth,
                                                ushort* __restrict__ ptl, int ip1) {
    __shared__ float tile[64][65];
    int tid = threadIdx.x, w = tid >> 6, l = tid & 63;
    int nloc = w * 16 + (l >> 2);
    int n = blockIdx.x * 64 + nloc;
    int f0 = (l & 3) * 16;
    size_t idx = (size_t)n * 64 + f0;
    float v[16];
#pragma unroll
    for (int q = 0; q < 4; ++q) {
        float4 tp = *(const float4*)&tpo[idx + q * 4];
        float4 rw = *(const float4*)&raw[idx + q * 4];
        float4 c0 = *(const float4*)&corrsum[idx + q * 4];
        float4 c1 = *(const float4*)&corrsum[(size_t)NPE + idx + q * 4];
        float tv[4] = {tp.x, tp.y, tp.z, tp.w};
        float rv[4] = {rw.x, rw.y, rw.z, rw.w};
        float cr[4] = {c0.x + c1.x, c0.y + c1.y, c0.z + c1.z, c0.w + c1.w};
#pragma unroll
        for (int e = 0; e < 4; ++e) {
            float x = 1.5f * tv[e] - 0.5f * cr[e];
            x = 0.1f * rv[e] + 0.9f * x;
            v[q * 4 + e] = tanhf(x);
        }
    }
#pragma unroll
    for (int q = 0; q < 4; ++q) {
        *(float4*)&pe[idx + q * 4] =
            make_float4(v[q * 4], v[q * 4 + 1], v[q * 4 + 2], v[q * 4 + 3]);
    }
    float g = 0.f;
#pragma unroll
    for (int f = 0; f < 16; ++f) g = fmaf(v[f], gw[ip1 * PEH + f0 + f], g);
    g += __shfl_xor(g, 1);
    g += __shfl_xor(g, 2);
    if ((l & 3) == 0) {
        float T = temp[ip1];
        T = T > 0.f ? T : 0.f;
        gamma[ip1 * N_NODES + n] = T / (1.f + expf(-(g + gb[ip1])));
    }
#pragma unroll
    for (int f = 0; f < 16; ++f) tile[nloc][f0 + f] = v[f];
    __syncthreads();
    int d = l, q = w;
    bf16x8 h0, h1, l0, l1;
#pragma unroll
    for (int c = 0; c < 8; ++c) {
        short hh, ll;
        split_bf16(tile[q * 16 + c][d], hh, ll);
        h0[c] = hh; l0[c] = ll;
    }
#pragma unroll
    for (int c = 0; c < 8; ++c) {
        short hh, ll;
        split_bf16(tile[q * 16 + 8 + c][d], hh, ll);
        h1[c] = hh; l1[c] = ll;
    }
    size_t ob = (size_t)d * N_NODES + blockIdx.x * 64 + q * 16;
    *(bf16x8*)&pth[ob] = h0;
    *(bf16x8*)&pth[ob + 8] = h1;
    *(bf16x8*)&ptl[ob] = l0;
    *(bf16x8*)&ptl[ob + 8] = l1;
}

// ---------------- SpMM width 128: y_m = A @ y_{m-1} ----------------
__global__ void k_spmm(const float* __restrict__ in, float* __restrict__ outp,
                       const int* __restrict__ rp, const int* __restrict__ col,
                       const float* __restrict__ w) {
    __shared__ int sc[128];
    __shared__ float sw[128];
    int r = blockIdx.x, t = threadIdx.x;
    int e0 = rp[r], e1 = rp[r + 1];
    float acc = 0.f;
    for (int ch = e0; ch < e1; ch += 128) {
        int n = min(128, e1 - ch);
        __syncthreads();
        if (t < n) { sc[t] = col[ch + t]; sw[t] = w[ch + t]; }
        __syncthreads();
        for (int q = 0; q < n; ++q)
            acc = fmaf(sw[q], in[(size_t)sc[q] * OUTD + t], acc);
    }
    outp[(size_t)r * OUTD + t] = acc;
}

// ---------------- epilogue: out[r] = sum_m delta_m[r] * y_m[r] ----------------
__global__ void k_out(const float* __restrict__ y, const float* __restrict__ gamma,
                      float* __restrict__ dout) {
    int r = blockIdx.x, t = threadIdx.x;  // 128 threads
    float g[11];
#pragma unroll
    for (int j = 0; j <= KHOP; ++j) g[j] = d_coeff[j] * gamma[j * N_NODES + r];
    float acc = 0.f;
#pragma unroll
    for (int m = 0; m <= KHOP; ++m) {
        float dm = 0.f;
#pragma unroll
        for (int j = 0; j <= KHOP; ++j) dm = fmaf(g[j], d_beta[j][m], dm);
        acc = fmaf(dm, y[(size_t)m * NM + (size_t)r * OUTD + t], acc);
    }
    dout[(size_t)r * OUTD + t] = acc;
}

__global__ void k_pecopy(const float* __restrict__ pe, float* __restrict__ dout) {
    int i = blockIdx.x * blockDim.x + threadIdx.x;
    if (i < NPE) dout[NM + i] = pe[i];
}

// ---------------- host launcher ----------------
extern "C" void kernel_launch(void* const* d_in, const int* in_sizes, int n_in,
                              void* d_out, int out_size, void* d_ws, size_t ws_size,
                              hipStream_t stream) {
    const float* node_feat = (const float*)d_in[0];
    const int*   eidx      = (const int*)d_in[1];
    const float* pos_enc   = (const float*)d_in[2];
    const float* lin1_w    = (const float*)d_in[3];
    const float* lin1_b    = (const float*)d_in[4];
    const float* lin2_w    = (const float*)d_in[5];
    const float* lin2_b    = (const float*)d_in[6];
    const float* pe_w      = (const float*)d_in[7];
    const float* pe_b      = (const float*)d_in[8];
    const float* cor_w     = (const float*)d_in[9];
    const float* cor_b     = (const float*)d_in[10];
    const float* gate_w    = (const float*)d_in[11];
    const float* gate_b    = (const float*)d_in[12];
    const float* temp      = (const float*)d_in[13];
    const int* src = eidx;
    const int* dst = eidx + E_EDGES;
    float* dout = (float*)d_out;

    char* p = (char*)d_ws;
    auto alloc = [&](size_t bytes) -> char* {
        char* r = p;
        p += (bytes + 255) & ~(size_t)255;
        return r;
    };
    int*    outdeg = (int*)alloc(N_NODES * 4);
    int*    indeg  = (int*)alloc(N_NODES * 4);
    int*    fill   = (int*)alloc(N_NODES * 4);
    int*    rp     = (int*)alloc((N_NODES + 1) * 4);
    int*    col    = (int*)alloc(E_EDGES * 4);
    float*  wl     = (float*)alloc(E_EDGES * 4);
    float*  wg     = (float*)alloc(E_EDGES * 4);
    float*  dinv   = (float*)alloc(N_NODES * 4);
    float*  d2     = (float*)alloc(N_NODES * 4);
    ushort* nfh    = (ushort*)alloc((size_t)N_NODES * IND * 2);
    ushort* nfl    = (ushort*)alloc((size_t)N_NODES * IND * 2);
    ushort* w1th   = (ushort*)alloc((size_t)HID * IND * 2);
    ushort* w1tl   = (ushort*)alloc((size_t)HID * IND * 2);
    ushort* w2th   = (ushort*)alloc((size_t)OUTD * HID * 2);
    ushort* w2tl   = (ushort*)alloc((size_t)OUTD * HID * 2);
    ushort* hh     = (ushort*)alloc((size_t)N_NODES * HID * 2);
    ushort* hl     = (ushort*)alloc((size_t)N_NODES * HID * 2);
    float*  pe     = (float*)alloc((size_t)NPE * 4);
    float*  raw    = (float*)alloc((size_t)NPE * 4);
    ushort* pth    = (ushort*)alloc((size_t)NPE * 2);
    ushort* ptl    = (ushort*)alloc((size_t)NPE * 2);
    ushort* ch     = (ushort*)alloc((size_t)NPE * 2);
    ushort* cl     = (ushort*)alloc((size_t)NPE * 2);
    float*  tpo    = (float*)alloc((size_t)NPE * 4);
    // pacc1 (33.55 MB) reused as corrp (NCHUNK=32 slices, exact fit);
    // pacc2 (8.4 MB) reused as corrsum (2 partial halves = 2 MB)
    float*  pacc1  = (float*)alloc((size_t)4 * N_NODES * HID * 4);
    float*  corrp  = pacc1;
    float*  pacc2  = (float*)alloc((size_t)4 * N_NODES * OUTD * 4);
    float*  corrsum= pacc2;
    float*  gamma  = (float*)alloc((size_t)11 * N_NODES * 4);
    float*  y      = (float*)alloc((size_t)11 * NM * 4);

    hipMemsetAsync(outdeg, 0, N_NODES * 4, stream);
    hipMemsetAsync(indeg, 0, N_NODES * 4, stream);
    hipMemsetAsync(fill, 0, N_NODES * 4, stream);

    k_degrees<<<E_EDGES / 256, 256, 0, stream>>>(src, dst, outdeg, indeg);
    k_invs<<<N_NODES / 256, 256, 0, stream>>>(outdeg, indeg, dinv, d2);
    k_scan<<<1, 64, 0, stream>>>(indeg, rp);
    k_scatter<<<E_EDGES / 256, 256, 0, stream>>>(src, dst, rp, fill, dinv, d2, col, wl, wg);

    // split inputs for MFMA encoder GEMMs
    k_split_rm<<<(N_NODES * IND / 8 + 255) / 256, 256, 0, stream>>>(
        node_feat, nfh, nfl, N_NODES * IND / 8);
    k_splitT<<<dim3(IND / 64, HID / 64), 256, 0, stream>>>(lin1_w, w1th, w1tl, IND, HID);
    k_splitT<<<dim3(HID / 64, OUTD / 64), 256, 0, stream>>>(lin2_w, w2th, w2tl, HID, OUTD);

    // x = relu(nf@W1+b1)@W2+b2 -> y slot 0   (K-split z=4, partial buffers)
    k_xgemm_z<IND, 256><<<dim3(64, 8, 4), 256, 0, stream>>>(nfh, nfl, w1th, w1tl,
                                                            pacc1, HID);
    k_finz<true, true><<<N_NODES * HID / 4 / 256, 256, 0, stream>>>(
        pacc1, lin1_b, nullptr, hh, hl, HID, N_NODES * HID);
    k_xgemm_z<HID, 128><<<dim3(64, 2, 4), 256, 0, stream>>>(hh, hl, w2th, w2tl,
                                                            pacc2, OUTD);
    k_finz<false, false><<<N_NODES * OUTD / 4 / 256, 256, 0, stream>>>(
        pacc2, lin2_b, y, nullptr, nullptr, OUTD, N_NODES * OUTD);

    k_pe0<<<N_NODES / 64, 256, 0, stream>>>(pos_enc, pe_w, pe_b, pe, raw, pth, ptl,
                                            gate_w, gate_b, temp, gamma);

    // monomial chain: y_m = A^m x
    for (int m = 1; m <= KHOP; ++m) {
        k_spmm<<<N_NODES, 128, 0, stream>>>(y + (size_t)(m - 1) * NM,
                                            y + (size_t)m * NM, rp, col, wl);
    }

    // pe loop — collects gamma[1..10]
    for (int i = 0; i < KHOP; ++i) {
        k_cmat<<<N_NODES / 4, dim3(64, 4), 0, stream>>>(pe, cor_w, cor_b, ch, cl);
        k_corr4<<<dim3(N_NODES / 64, NCHUNK), 256, 0, stream>>>(ch, cl, pth, ptl, corrp);
        k_csum<<<dim3(NPE / 4 / 256, 2), 256, 0, stream>>>(corrp, corrsum);
        k_ahat<<<N_NODES, 64, 0, stream>>>(pe, tpo, rp, col, wg, d2);
        k_update<<<N_NODES / 64, 256, 0, stream>>>(tpo, corrsum, raw, pe, gate_w,
                                                   gate_b, temp, gamma, pth, ptl, i + 1);
    }

    k_out<<<N_NODES, 128, 0, stream>>>(y, gamma, dout);
    k_pecopy<<<(NPE + 255) / 256, 256, 0, stream>>>(pe, dout);
}

// Round 6
// 766.257 us; speedup vs baseline: 1.6543x; 1.6543x over previous
//
#include <hip/hip_runtime.h>
#include <math.h>

constexpr int N_NODES = 4096;
constexpr int E_EDGES = 131072;
constexpr int IND     = 1024;
constexpr int HID     = 512;
constexpr int OUTD    = 128;
constexpr int PEH     = 64;
constexpr int KHOP    = 10;
constexpr int NPE     = N_NODES * PEH;    // 262144
constexpr int NM      = N_NODES * OUTD;   // 524288
constexpr int NCHUNK  = 16;               // corr column chunks (256 cols each)

__constant__ float d_coeff[11] = {
    1.f/1024.f, 10.f/1024.f, 45.f/1024.f, 120.f/1024.f, 210.f/1024.f,
    252.f/1024.f, 210.f/1024.f, 120.f/1024.f, 45.f/1024.f, 10.f/1024.f, 1.f/1024.f};

// beta[j][m]: (1-t)^j (1+t)^(10-j) = sum_m beta[j][m] t^m
__constant__ float d_beta[11][11] = {
    {1,  10, 45, 120, 210, 252, 210, 120, 45, 10, 1},
    {1,   8, 27,  48,  42,   0, -42, -48, -27, -8, -1},
    {1,   6, 13,   8, -14, -28, -14,   8,  13,  6,  1},
    {1,   4,  3,  -8, -14,   0,  14,   8,  -3, -4, -1},
    {1,   2, -3,  -8,   2,  12,   2,  -8,  -3,  2,  1},
    {1,   0, -5,   0,  10,   0, -10,   0,   5,  0, -1},
    {1,  -2, -3,   8,   2, -12,   2,   8,  -3, -2,  1},
    {1,  -4,  3,   8, -14,   0,  14,  -8,  -3,  4, -1},
    {1,  -6, 13,  -8, -14,  28, -14,  -8,  13, -6,  1},
    {1,  -8, 27, -48,  42,   0, -42,  48, -27,  8, -1},
    {1, -10, 45, -120, 210, -252, 210, -120, 45, -10, 1}};

typedef __attribute__((ext_vector_type(8))) short bf16x8;
typedef __attribute__((ext_vector_type(4))) float f32x4;

__device__ __forceinline__ void split_bf16(float x, short& h, short& l) {
    unsigned bx = __float_as_uint(x);
    h = (short)(bx >> 16);
    float hf = __uint_as_float(bx & 0xffff0000u);
    l = (short)(__float_as_uint(x - hf) >> 16);
}

// fragment-major pack index: matrix M[16*G rows][64*T k], fragment element
// (g, t, h, lane=lq*16+lm, e) <-> M[g*16+lm][t*64 + h*32 + lq*8 + e]
__device__ __forceinline__ size_t fidx(int g, int T, int t, int h, int lane) {
    return ((((size_t)g * T + t) * 2 + h) * 64 + lane) * 8;
}

// element index into a 64x64 ushort LDS tile, XOR-swizzled at 16B granularity
__device__ __forceinline__ int swz(int row, int col) {
    return row * 64 + (col ^ ((row & 7) << 3));
}

// ---------------- graph prep ----------------
__global__ void k_degrees(const int* __restrict__ src, const int* __restrict__ dst,
                          int* outdeg, int* indeg) {
    int e = blockIdx.x * blockDim.x + threadIdx.x;
    if (e < E_EDGES) {
        atomicAdd(&outdeg[src[e]], 1);
        atomicAdd(&indeg[dst[e]], 1);
    }
}

__global__ void k_invs(const int* __restrict__ outdeg, const int* __restrict__ indeg,
                       float* dinv, float* d2) {
    int i = blockIdx.x * blockDim.x + threadIdx.x;
    if (i < N_NODES) {
        int od = outdeg[i];
        dinv[i] = od > 0 ? 1.0f / sqrtf((float)od) : 0.0f;
        d2[i]   = 1.0f / sqrtf((float)indeg[i] + 1.0f);
    }
}

__global__ void k_scan(const int* __restrict__ cnt, int* __restrict__ rp) {
    int lane = threadIdx.x;  // 0..63
    int base = lane * 64;
    int sum = 0;
    for (int j = 0; j < 64; ++j) sum += cnt[base + j];
    int incl = sum;
    for (int off = 1; off < 64; off <<= 1) {
        int nv = __shfl_up(incl, off);
        if (lane >= off) incl += nv;
    }
    int run = incl - sum;
    for (int j = 0; j < 64; ++j) { rp[base + j] = run; run += cnt[base + j]; }
    if (lane == 63) rp[N_NODES] = run;
}

__global__ void k_scatter(const int* __restrict__ src, const int* __restrict__ dst,
                          const int* __restrict__ rp, int* __restrict__ fill,
                          const float* __restrict__ dinv, const float* __restrict__ d2,
                          int* __restrict__ col, float* __restrict__ wl,
                          float* __restrict__ wg) {
    int e = blockIdx.x * blockDim.x + threadIdx.x;
    if (e < E_EDGES) {
        int s = src[e], d = dst[e];
        int pos = rp[d] + atomicAdd(&fill[d], 1);
        col[pos] = s;
        wl[pos]  = dinv[s] * dinv[d];
        wg[pos]  = d2[s] * d2[d];
    }
}

// -------- pack node_feat: row-major f32 -> fragment-major hi/lo bf16 ----------
__global__ void k_split_rm(const float* __restrict__ in, ushort* __restrict__ oh,
                           ushort* __restrict__ ol, int total8) {
    int i = blockIdx.x * blockDim.x + threadIdx.x;
    if (i >= total8) return;
    int r = i >> 7, c8 = i & 127;      // IND/8 = 128
    float4 f0 = *(const float4*)&in[(size_t)i * 8];
    float4 f1 = *(const float4*)&in[(size_t)i * 8 + 4];
    float v[8] = {f0.x, f0.y, f0.z, f0.w, f1.x, f1.y, f1.z, f1.w};
    bf16x8 h, l;
#pragma unroll
    for (int j = 0; j < 8; ++j) {
        short hh, ll;
        split_bf16(v[j], hh, ll);
        h[j] = hh; l[j] = ll;
    }
    int t = c8 >> 3, hh2 = (c8 >> 2) & 1, lq = c8 & 3;
    size_t a = fidx(r >> 4, IND / 64, t, hh2, lq * 16 + (r & 15));
    *(bf16x8*)&oh[a] = h;
    *(bf16x8*)&ol[a] = l;
}

// ---- weights: f32 [R][C] -> fragment-major hi/lo bf16 of the transpose -------
// output matrix rows = C (G=C/16 groups), k-dim = R (T = R/64)
__global__ __launch_bounds__(256) void k_splitT(const float* __restrict__ in,
                                                ushort* __restrict__ th,
                                                ushort* __restrict__ tl,
                                                int R, int C) {
    __shared__ float tile[64][65];
    int tid = threadIdx.x;
    int r0 = blockIdx.x * 64, c0 = blockIdx.y * 64;
    int row = tid >> 2, cq = (tid & 3) * 16;
#pragma unroll
    for (int q = 0; q < 4; ++q) {
        float4 f = *(const float4*)&in[(size_t)(r0 + row) * C + c0 + cq + q * 4];
        tile[row][cq + q * 4 + 0] = f.x;
        tile[row][cq + q * 4 + 1] = f.y;
        tile[row][cq + q * 4 + 2] = f.z;
        tile[row][cq + q * 4 + 3] = f.w;
    }
    __syncthreads();
    int d = tid & 63, q = tid >> 6;
    bf16x8 h0, h1, l0, l1;
#pragma unroll
    for (int c = 0; c < 8; ++c) {
        short hh, ll;
        split_bf16(tile[q * 16 + c][d], hh, ll);
        h0[c] = hh; l0[c] = ll;
    }
#pragma unroll
    for (int c = 0; c < 8; ++c) {
        short hh, ll;
        split_bf16(tile[q * 16 + 8 + c][d], hh, ll);
        h1[c] = hh; l1[c] = ll;
    }
    int T = R / 64;
    int g = (c0 + d) >> 4, lm = (c0 + d) & 15, t = r0 >> 6, hh2 = q >> 1;
    size_t a0 = fidx(g, T, t, hh2, ((2 * q) & 3) * 16 + lm);
    size_t a1 = fidx(g, T, t, hh2, ((2 * q + 1) & 3) * 16 + lm);
    *(bf16x8*)&th[a0] = h0;
    *(bf16x8*)&th[a1] = h1;
    *(bf16x8*)&tl[a0] = l0;
    *(bf16x8*)&tl[a1] = l1;
}

// ------- MFMA GEMM, K-split, packed operands, lane-major partial out ----------
template <int T, int KCH>
__global__ __launch_bounds__(256) void k_xgemm_zp(const ushort* __restrict__ apkh,
                                                  const ushort* __restrict__ apkl,
                                                  const ushort* __restrict__ bpkh,
                                                  const ushort* __restrict__ bpkl,
                                                  float* __restrict__ pout) {
    int tid = threadIdx.x;
    int w = tid >> 6, l = tid & 63;
    int ga = blockIdx.x * 4 + w;       // row-group (16 rows)
    int gb0 = blockIdx.y * 4;          // first col-group
    int t0 = blockIdx.z * (KCH / 64);
    f32x4 acc[4];
#pragma unroll
    for (int n = 0; n < 4; ++n) acc[n] = (f32x4){0.f, 0.f, 0.f, 0.f};
    for (int kk = 0; kk < KCH / 64; ++kk) {
        int t = t0 + kk;
        bf16x8 Ah0 = *(const bf16x8*)&apkh[fidx(ga, T, t, 0, l)];
        bf16x8 Ah1 = *(const bf16x8*)&apkh[fidx(ga, T, t, 1, l)];
        bf16x8 Al0 = *(const bf16x8*)&apkl[fidx(ga, T, t, 0, l)];
        bf16x8 Al1 = *(const bf16x8*)&apkl[fidx(ga, T, t, 1, l)];
#pragma unroll
        for (int n = 0; n < 4; ++n) {
            bf16x8 Bh0 = *(const bf16x8*)&bpkh[fidx(gb0 + n, T, t, 0, l)];
            bf16x8 Bh1 = *(const bf16x8*)&bpkh[fidx(gb0 + n, T, t, 1, l)];
            bf16x8 Bl0 = *(const bf16x8*)&bpkl[fidx(gb0 + n, T, t, 0, l)];
            bf16x8 Bl1 = *(const bf16x8*)&bpkl[fidx(gb0 + n, T, t, 1, l)];
            acc[n] = __builtin_amdgcn_mfma_f32_16x16x32_bf16(Ah0, Bh0, acc[n], 0, 0, 0);
            acc[n] = __builtin_amdgcn_mfma_f32_16x16x32_bf16(Ah1, Bh1, acc[n], 0, 0, 0);
            acc[n] = __builtin_amdgcn_mfma_f32_16x16x32_bf16(Ah0, Bl0, acc[n], 0, 0, 0);
            acc[n] = __builtin_amdgcn_mfma_f32_16x16x32_bf16(Ah1, Bl1, acc[n], 0, 0, 0);
            acc[n] = __builtin_amdgcn_mfma_f32_16x16x32_bf16(Al0, Bh0, acc[n], 0, 0, 0);
            acc[n] = __builtin_amdgcn_mfma_f32_16x16x32_bf16(Al1, Bh1, acc[n], 0, 0, 0);
        }
    }
    // lane-major block-tile partial: [(z*GX+bx)*GY+by][w*16+n*4+r][lane]
    size_t base = ((((size_t)blockIdx.z * gridDim.x + blockIdx.x) * gridDim.y)
                   + blockIdx.y) * 4096;
#pragma unroll
    for (int n = 0; n < 4; ++n) {
#pragma unroll
        for (int r = 0; r < 4; ++r) {
            pout[base + (size_t)(w * 16 + n * 4 + r) * 64 + l] = acc[n][r];
        }
    }
}

// reduce z=4 lane-major partials + bias (+relu) -> row-major f32 or packed bf16
template <int NC, bool RELU, bool SPLIT>
__global__ void k_finzp(const float* __restrict__ pin, const float* __restrict__ bias,
                        float* __restrict__ outf, ushort* __restrict__ oh,
                        ushort* __restrict__ ol) {
    constexpr int GY = NC / 64;
    constexpr size_t ZSTEP = (size_t)64 * GY * 4096;
    int i8 = blockIdx.x * blockDim.x + threadIdx.x;
    int r = i8 / (NC / 8), c = (i8 % (NC / 8)) * 8;
    int bx = r >> 6, w = (r >> 4) & 3, lq = (r >> 2) & 3, rr = r & 3;
    int by = c >> 6, n = (c >> 4) & 3, lm0 = c & 15;
    size_t base = (((size_t)bx * GY) + by) * 4096
                  + (size_t)(w * 16 + n * 4 + rr) * 64 + lq * 16 + lm0;
    float v[8];
#pragma unroll
    for (int j = 0; j < 8; ++j) v[j] = bias[c + j];
#pragma unroll
    for (int z = 0; z < 4; ++z) {
        float4 p0 = *(const float4*)&pin[base + z * ZSTEP];
        float4 p1 = *(const float4*)&pin[base + z * ZSTEP + 4];
        v[0] += p0.x; v[1] += p0.y; v[2] += p0.z; v[3] += p0.w;
        v[4] += p1.x; v[5] += p1.y; v[6] += p1.z; v[7] += p1.w;
    }
    if (RELU) {
#pragma unroll
        for (int j = 0; j < 8; ++j) v[j] = fmaxf(v[j], 0.f);
    }
    if (SPLIT) {
        bf16x8 h, lo;
#pragma unroll
        for (int j = 0; j < 8; ++j) {
            short hh, ll;
            split_bf16(v[j], hh, ll);
            h[j] = hh; lo[j] = ll;
        }
        size_t a = fidx(r >> 4, NC / 64, c >> 6, (c >> 5) & 1,
                        ((c >> 3) & 3) * 16 + (r & 15));
        *(bf16x8*)&oh[a] = h;
        *(bf16x8*)&ol[a] = lo;
    } else {
        *(float4*)&outf[(size_t)r * NC + c] =
            make_float4(v[0], v[1], v[2], v[3]);
        *(float4*)&outf[(size_t)r * NC + c + 4] =
            make_float4(v[4], v[5], v[6], v[7]);
    }
}

// -------- PE encoder: pe = tanh(pos_enc @ pe_w + pe_b), fused gamma[0],
// writes pe/raw f32 + fragment-packed peT (hi/lo) ------------------------------
__global__ __launch_bounds__(256) void k_pe0(const float* __restrict__ pos_enc,
                                             const float* __restrict__ pw,
                                             const float* __restrict__ pb,
                                             float* __restrict__ pe,
                                             float* __restrict__ raw,
                                             ushort* __restrict__ pthpk,
                                             ushort* __restrict__ ptlpk,
                                             const float* __restrict__ gw,
                                             const float* __restrict__ gb,
                                             const float* __restrict__ temp,
                                             float* __restrict__ gamma) {
    __shared__ float tile[64][65];
    int tid = threadIdx.x, w = tid >> 6, l = tid & 63;
    int nloc = w * 16 + (l >> 2);
    int nn = blockIdx.x * 64 + nloc;
    int f0 = (l & 3) * 16;
    float v[16];
#pragma unroll
    for (int f = 0; f < 16; ++f) v[f] = pb[f0 + f];
    for (int k0 = 0; k0 < 128; k0 += 4) {
        float4 pv = *(const float4*)&pos_enc[(size_t)nn * 128 + k0];
        float pa[4] = {pv.x, pv.y, pv.z, pv.w};
#pragma unroll
        for (int kk = 0; kk < 4; ++kk) {
            const float* wr = &pw[(size_t)(k0 + kk) * 64 + f0];
            float4 w0 = *(const float4*)&wr[0];
            float4 w1 = *(const float4*)&wr[4];
            float4 w2 = *(const float4*)&wr[8];
            float4 w3 = *(const float4*)&wr[12];
            float wv[16] = {w0.x, w0.y, w0.z, w0.w, w1.x, w1.y, w1.z, w1.w,
                            w2.x, w2.y, w2.z, w2.w, w3.x, w3.y, w3.z, w3.w};
#pragma unroll
            for (int f = 0; f < 16; ++f) v[f] = fmaf(pa[kk], wv[f], v[f]);
        }
    }
#pragma unroll
    for (int f = 0; f < 16; ++f) v[f] = tanhf(v[f]);
#pragma unroll
    for (int q = 0; q < 4; ++q) {
        float4 fv = make_float4(v[q * 4], v[q * 4 + 1], v[q * 4 + 2], v[q * 4 + 3]);
        *(float4*)&pe[(size_t)nn * 64 + f0 + q * 4] = fv;
        *(float4*)&raw[(size_t)nn * 64 + f0 + q * 4] = fv;
    }
    float g = 0.f;
#pragma unroll
    for (int f = 0; f < 16; ++f) g = fmaf(v[f], gw[f0 + f], g);
    g += __shfl_xor(g, 1);
    g += __shfl_xor(g, 2);
    if ((l & 3) == 0) {
        float T = temp[0];
        T = T > 0.f ? T : 0.f;
        gamma[nn] = T / (1.f + expf(-(g + gb[0])));
    }
#pragma unroll
    for (int f = 0; f < 16; ++f) tile[nloc][f0 + f] = v[f];
    __syncthreads();
    int d = l, q = w;
    bf16x8 h0, h1, l0, l1;
#pragma unroll
    for (int c = 0; c < 8; ++c) {
        short hh, ll;
        split_bf16(tile[q * 16 + c][d], hh, ll);
        h0[c] = hh; l0[c] = ll;
    }
#pragma unroll
    for (int c = 0; c < 8; ++c) {
        short hh, ll;
        split_bf16(tile[q * 16 + 8 + c][d], hh, ll);
        h1[c] = hh; l1[c] = ll;
    }
    int ng = d >> 4, lm = d & 15, tcb = blockIdx.x, hh2 = q >> 1;
    size_t a0 = fidx(ng, 64, tcb, hh2, ((2 * q) & 3) * 16 + lm);
    size_t a1 = fidx(ng, 64, tcb, hh2, ((2 * q + 1) & 3) * 16 + lm);
    *(bf16x8*)&pthpk[a0] = h0;
    *(bf16x8*)&pthpk[a1] = h1;
    *(bf16x8*)&ptlpk[a0] = l0;
    *(bf16x8*)&ptlpk[a1] = l1;
}

// -------- c = pe @ cor_w + cor_b -> fragment-packed hi/lo bf16 ----------------
__global__ void k_cmat(const float* __restrict__ pe, const float* __restrict__ cw,
                       const float* __restrict__ cb, ushort* __restrict__ chpk,
                       ushort* __restrict__ clpk) {
    int t = threadIdx.x;
    int r = blockIdx.x * 4 + threadIdx.y;
    float acc = cb[t];
    for (int k = 0; k < PEH; ++k)
        acc = fmaf(pe[(size_t)r * PEH + k], cw[k * PEH + t], acc);
    short hh, ll;
    split_bf16(acc, hh, ll);
    size_t a = fidx(r >> 4, 1, 0, t >> 5, ((t >> 3) & 3) * 16 + (r & 15)) + (t & 7);
    chpk[a] = (ushort)hh;
    clpk[a] = (ushort)ll;
}

// ======== corr5: sigmoid(c c^T) @ pe partials; packed coalesced fragments =====
__global__ __launch_bounds__(256) void k_corr5(const ushort* __restrict__ chpk,
                                               const ushort* __restrict__ clpk,
                                               const ushort* __restrict__ pthpk,
                                               const ushort* __restrict__ ptlpk,
                                               float* __restrict__ part) {
    __shared__ __align__(16) ushort Sh[4096];
    __shared__ __align__(16) ushort Sl[4096];
    int tid = threadIdx.x, w = tid >> 6, l = tid & 63;
    int lm = l & 15, lq = l >> 4, wrow = w * 16;
    int chunk = blockIdx.y;  // 0..15, 256 cols each

    int ga = blockIdx.x * 4 + w;
    bf16x8 cAh0 = *(const bf16x8*)&chpk[fidx(ga, 1, 0, 0, l)];
    bf16x8 cAh1 = *(const bf16x8*)&chpk[fidx(ga, 1, 0, 1, l)];
    bf16x8 cAl0 = *(const bf16x8*)&clpk[fidx(ga, 1, 0, 0, l)];
    bf16x8 cAl1 = *(const bf16x8*)&clpk[fidx(ga, 1, 0, 1, l)];

    f32x4 pacc[4];
#pragma unroll
    for (int n = 0; n < 4; ++n) pacc[n] = (f32x4){0.f, 0.f, 0.f, 0.f};

#pragma unroll
    for (int tt = 0; tt < 4; ++tt) {
        // GEMM1: S = cR @ cC^T (hh + hl + lh); per-n finalize into LDS strip
#pragma unroll
        for (int n = 0; n < 4; ++n) {
            int gb = chunk * 16 + tt * 4 + n;
            bf16x8 Bh0 = *(const bf16x8*)&chpk[fidx(gb, 1, 0, 0, l)];
            bf16x8 Bh1 = *(const bf16x8*)&chpk[fidx(gb, 1, 0, 1, l)];
            bf16x8 Bl0 = *(const bf16x8*)&clpk[fidx(gb, 1, 0, 0, l)];
            bf16x8 Bl1 = *(const bf16x8*)&clpk[fidx(gb, 1, 0, 1, l)];
            f32x4 sacc = (f32x4){0.f, 0.f, 0.f, 0.f};
            sacc = __builtin_amdgcn_mfma_f32_16x16x32_bf16(cAh0, Bh0, sacc, 0, 0, 0);
            sacc = __builtin_amdgcn_mfma_f32_16x16x32_bf16(cAh1, Bh1, sacc, 0, 0, 0);
            sacc = __builtin_amdgcn_mfma_f32_16x16x32_bf16(cAh0, Bl0, sacc, 0, 0, 0);
            sacc = __builtin_amdgcn_mfma_f32_16x16x32_bf16(cAh1, Bl1, sacc, 0, 0, 0);
            sacc = __builtin_amdgcn_mfma_f32_16x16x32_bf16(cAl0, Bh0, sacc, 0, 0, 0);
            sacc = __builtin_amdgcn_mfma_f32_16x16x32_bf16(cAl1, Bh1, sacc, 0, 0, 0);
#pragma unroll
            for (int r = 0; r < 4; ++r) {
                float sg = 1.0f / (1.0f + __expf(-sacc[r]));
                short hh, ll;
                split_bf16(sg, hh, ll);
                int iw = swz(wrow + lq * 4 + r, n * 16 + lm);
                Sh[iw] = (ushort)hh;
                Sl[iw] = (ushort)ll;
            }
        }
        // GEMM2: P += sig(S) @ pe; A from wave-private LDS strip
        bf16x8 sAh0 = *(const bf16x8*)&Sh[swz(wrow + lm, lq * 8)];
        bf16x8 sAh1 = *(const bf16x8*)&Sh[swz(wrow + lm, 32 + lq * 8)];
        bf16x8 sAl0 = *(const bf16x8*)&Sl[swz(wrow + lm, lq * 8)];
        bf16x8 sAl1 = *(const bf16x8*)&Sl[swz(wrow + lm, 32 + lq * 8)];
        int tc = chunk * 4 + tt;
#pragma unroll
        for (int n = 0; n < 4; ++n) {
            bf16x8 Ph0 = *(const bf16x8*)&pthpk[fidx(n, 64, tc, 0, l)];
            bf16x8 Ph1 = *(const bf16x8*)&pthpk[fidx(n, 64, tc, 1, l)];
            bf16x8 Pl0 = *(const bf16x8*)&ptlpk[fidx(n, 64, tc, 0, l)];
            bf16x8 Pl1 = *(const bf16x8*)&ptlpk[fidx(n, 64, tc, 1, l)];
            pacc[n] = __builtin_amdgcn_mfma_f32_16x16x32_bf16(sAh0, Ph0, pacc[n], 0, 0, 0);
            pacc[n] = __builtin_amdgcn_mfma_f32_16x16x32_bf16(sAh1, Ph1, pacc[n], 0, 0, 0);
            pacc[n] = __builtin_amdgcn_mfma_f32_16x16x32_bf16(sAh0, Pl0, pacc[n], 0, 0, 0);
            pacc[n] = __builtin_amdgcn_mfma_f32_16x16x32_bf16(sAh1, Pl1, pacc[n], 0, 0, 0);
            pacc[n] = __builtin_amdgcn_mfma_f32_16x16x32_bf16(sAl0, Ph0, pacc[n], 0, 0, 0);
            pacc[n] = __builtin_amdgcn_mfma_f32_16x16x32_bf16(sAl1, Ph1, pacc[n], 0, 0, 0);
        }
    }
    // lane-major partial tile: [(chunk*64 + bx)*4096 + (w*16+n*4+r)*64 + l]
    size_t base = ((size_t)chunk * 64 + blockIdx.x) * 4096;
#pragma unroll
    for (int n = 0; n < 4; ++n) {
#pragma unroll
        for (int r = 0; r < 4; ++r) {
            part[base + (size_t)(w * 16 + n * 4 + r) * 64 + l] = pacc[n][r];
        }
    }
}

// ---- reduce corr lane-major partials -> row-major corrsum (2 halves) ---------
__global__ void k_csum(const float* __restrict__ corrp, float* __restrict__ corrsum) {
    int i8 = blockIdx.x * blockDim.x + threadIdx.x;  // NPE/8 per half
    int half = blockIdx.y;
    int r = i8 >> 3, d = (i8 & 7) * 8;
    int bx = r >> 6, w = (r >> 4) & 3, lq = (r >> 2) & 3, rr = r & 3;
    int n = (d >> 4) & 3, lm0 = d & 15;
    size_t inblk = (size_t)(w * 16 + n * 4 + rr) * 64 + lq * 16 + lm0;
    float v[8] = {0.f, 0.f, 0.f, 0.f, 0.f, 0.f, 0.f, 0.f};
#pragma unroll
    for (int p = 0; p < 8; ++p) {
        int chunk = half * 8 + p;
        const float* s = &corrp[((size_t)chunk * 64 + bx) * 4096 + inblk];
        float4 p0 = *(const float4*)&s[0];
        float4 p1 = *(const float4*)&s[4];
        v[0] += p0.x; v[1] += p0.y; v[2] += p0.z; v[3] += p0.w;
        v[4] += p1.x; v[5] += p1.y; v[6] += p1.z; v[7] += p1.w;
    }
    float* o = &corrsum[(size_t)half * NPE + (size_t)r * 64 + d];
    *(float4*)&o[0] = make_float4(v[0], v[1], v[2], v[3]);
    *(float4*)&o[4] = make_float4(v[4], v[5], v[6], v[7]);
}

// ---------------- ahat (CSR SpMM width 64 + diag) ----------------
__global__ void k_ahat(const float* __restrict__ pe, float* __restrict__ tpo,
                       const int* __restrict__ rp, const int* __restrict__ col,
                       const float* __restrict__ wg, const float* __restrict__ d2) {
    __shared__ int sc[64];
    __shared__ float sw[64];
    int r = blockIdx.x, t = threadIdx.x;
    int e0 = rp[r], e1 = rp[r + 1];
    float dd = d2[r];
    float acc = dd * dd * pe[(size_t)r * PEH + t];
    for (int ch = e0; ch < e1; ch += 64) {
        int n = min(64, e1 - ch);
        __syncthreads();
        if (t < n) { sc[t] = col[ch + t]; sw[t] = wg[ch + t]; }
        __syncthreads();
        for (int q = 0; q < n; ++q)
            acc = fmaf(sw[q], pe[(size_t)sc[q] * PEH + t], acc);
    }
    tpo[(size_t)r * PEH + t] = acc;
}

// ---------------- pe update: pe, gamma, fragment-packed peT -------------------
__global__ __launch_bounds__(256) void k_update(const float* __restrict__ tpo,
                                                const float* __restrict__ corrsum,
                                                const float* __restrict__ raw,
                                                float* __restrict__ pe,
                                                const float* __restrict__ gw,
                                                const float* __restrict__ gb,
                                                const float* __restrict__ temp,
                                                float* __restrict__ gamma,
                                                ushort* __restrict__ pthpk,
                                                ushort* __restrict__ ptlpk, int ip1) {
    __shared__ float tile[64][65];
    int tid = threadIdx.x, w = tid >> 6, l = tid & 63;
    int nloc = w * 16 + (l >> 2);
    int nn = blockIdx.x * 64 + nloc;
    int f0 = (l & 3) * 16;
    size_t idx = (size_t)nn * 64 + f0;
    float v[16];
#pragma unroll
    for (int q = 0; q < 4; ++q) {
        float4 tp = *(const float4*)&tpo[idx + q * 4];
        float4 rw = *(const float4*)&raw[idx + q * 4];
        float4 c0 = *(const float4*)&corrsum[idx + q * 4];
        float4 c1 = *(const float4*)&corrsum[(size_t)NPE + idx + q * 4];
        float tv[4] = {tp.x, tp.y, tp.z, tp.w};
        float rv[4] = {rw.x, rw.y, rw.z, rw.w};
        float cr[4] = {c0.x + c1.x, c0.y + c1.y, c0.z + c1.z, c0.w + c1.w};
#pragma unroll
        for (int e = 0; e < 4; ++e) {
            float x = 1.5f * tv[e] - 0.5f * cr[e];
            x = 0.1f * rv[e] + 0.9f * x;
            v[q * 4 + e] = tanhf(x);
        }
    }
#pragma unroll
    for (int q = 0; q < 4; ++q) {
        *(float4*)&pe[idx + q * 4] =
            make_float4(v[q * 4], v[q * 4 + 1], v[q * 4 + 2], v[q * 4 + 3]);
    }
    float g = 0.f;
#pragma unroll
    for (int f = 0; f < 16; ++f) g = fmaf(v[f], gw[ip1 * PEH + f0 + f], g);
    g += __shfl_xor(g, 1);
    g += __shfl_xor(g, 2);
    if ((l & 3) == 0) {
        float T = temp[ip1];
        T = T > 0.f ? T : 0.f;
        gamma[ip1 * N_NODES + nn] = T / (1.f + expf(-(g + gb[ip1])));
    }
#pragma unroll
    for (int f = 0; f < 16; ++f) tile[nloc][f0 + f] = v[f];
    __syncthreads();
    int d = l, q = w;
    bf16x8 h0, h1, l0, l1;
#pragma unroll
    for (int c = 0; c < 8; ++c) {
        short hh, ll;
        split_bf16(tile[q * 16 + c][d], hh, ll);
        h0[c] = hh; l0[c] = ll;
    }
#pragma unroll
    for (int c = 0; c < 8; ++c) {
        short hh, ll;
        split_bf16(tile[q * 16 + 8 + c][d], hh, ll);
        h1[c] = hh; l1[c] = ll;
    }
    int ng = d >> 4, lm = d & 15, tcb = blockIdx.x, hh2 = q >> 1;
    size_t a0 = fidx(ng, 64, tcb, hh2, ((2 * q) & 3) * 16 + lm);
    size_t a1 = fidx(ng, 64, tcb, hh2, ((2 * q + 1) & 3) * 16 + lm);
    *(bf16x8*)&pthpk[a0] = h0;
    *(bf16x8*)&pthpk[a1] = h1;
    *(bf16x8*)&ptlpk[a0] = l0;
    *(bf16x8*)&ptlpk[a1] = l1;
}

// ---------------- SpMM width 128: y_m = A @ y_{m-1} ----------------
__global__ void k_spmm(const float* __restrict__ in, float* __restrict__ outp,
                       const int* __restrict__ rp, const int* __restrict__ col,
                       const float* __restrict__ w) {
    __shared__ int sc[128];
    __shared__ float sw[128];
    int r = blockIdx.x, t = threadIdx.x;
    int e0 = rp[r], e1 = rp[r + 1];
    float acc = 0.f;
    for (int ch = e0; ch < e1; ch += 128) {
        int n = min(128, e1 - ch);
        __syncthreads();
        if (t < n) { sc[t] = col[ch + t]; sw[t] = w[ch + t]; }
        __syncthreads();
        for (int q = 0; q < n; ++q)
            acc = fmaf(sw[q], in[(size_t)sc[q] * OUTD + t], acc);
    }
    outp[(size_t)r * OUTD + t] = acc;
}

// ---------------- epilogue: out[r] = sum_m delta_m[r] * y_m[r] ----------------
__global__ void k_out(const float* __restrict__ y, const float* __restrict__ gamma,
                      float* __restrict__ dout) {
    int r = blockIdx.x, t = threadIdx.x;  // 128 threads
    float g[11];
#pragma unroll
    for (int j = 0; j <= KHOP; ++j) g[j] = d_coeff[j] * gamma[j * N_NODES + r];
    float acc = 0.f;
#pragma unroll
    for (int m = 0; m <= KHOP; ++m) {
        float dm = 0.f;
#pragma unroll
        for (int j = 0; j <= KHOP; ++j) dm = fmaf(g[j], d_beta[j][m], dm);
        acc = fmaf(dm, y[(size_t)m * NM + (size_t)r * OUTD + t], acc);
    }
    dout[(size_t)r * OUTD + t] = acc;
}

__global__ void k_pecopy(const float* __restrict__ pe, float* __restrict__ dout) {
    int i = blockIdx.x * blockDim.x + threadIdx.x;
    if (i < NPE) dout[NM + i] = pe[i];
}

// ---------------- host launcher ----------------
extern "C" void kernel_launch(void* const* d_in, const int* in_sizes, int n_in,
                              void* d_out, int out_size, void* d_ws, size_t ws_size,
                              hipStream_t stream) {
    const float* node_feat = (const float*)d_in[0];
    const int*   eidx      = (const int*)d_in[1];
    const float* pos_enc   = (const float*)d_in[2];
    const float* lin1_w    = (const float*)d_in[3];
    const float* lin1_b    = (const float*)d_in[4];
    const float* lin2_w    = (const float*)d_in[5];
    const float* lin2_b    = (const float*)d_in[6];
    const float* pe_w      = (const float*)d_in[7];
    const float* pe_b      = (const float*)d_in[8];
    const float* cor_w     = (const float*)d_in[9];
    const float* cor_b     = (const float*)d_in[10];
    const float* gate_w    = (const float*)d_in[11];
    const float* gate_b    = (const float*)d_in[12];
    const float* temp      = (const float*)d_in[13];
    const int* src = eidx;
    const int* dst = eidx + E_EDGES;
    float* dout = (float*)d_out;

    char* p = (char*)d_ws;
    auto alloc = [&](size_t bytes) -> char* {
        char* r = p;
        p += (bytes + 255) & ~(size_t)255;
        return r;
    };
    int*    outdeg = (int*)alloc(N_NODES * 4);
    int*    indeg  = (int*)alloc(N_NODES * 4);
    int*    fill   = (int*)alloc(N_NODES * 4);
    int*    rp     = (int*)alloc((N_NODES + 1) * 4);
    int*    col    = (int*)alloc(E_EDGES * 4);
    float*  wl     = (float*)alloc(E_EDGES * 4);
    float*  wg     = (float*)alloc(E_EDGES * 4);
    float*  dinv   = (float*)alloc(N_NODES * 4);
    float*  d2     = (float*)alloc(N_NODES * 4);
    ushort* nfh    = (ushort*)alloc((size_t)N_NODES * IND * 2);
    ushort* nfl    = (ushort*)alloc((size_t)N_NODES * IND * 2);
    ushort* w1th   = (ushort*)alloc((size_t)HID * IND * 2);
    ushort* w1tl   = (ushort*)alloc((size_t)HID * IND * 2);
    ushort* w2th   = (ushort*)alloc((size_t)OUTD * HID * 2);
    ushort* w2tl   = (ushort*)alloc((size_t)OUTD * HID * 2);
    ushort* hh     = (ushort*)alloc((size_t)N_NODES * HID * 2);
    ushort* hl     = (ushort*)alloc((size_t)N_NODES * HID * 2);
    float*  pe     = (float*)alloc((size_t)NPE * 4);
    float*  raw    = (float*)alloc((size_t)NPE * 4);
    ushort* pth    = (ushort*)alloc((size_t)NPE * 2);
    ushort* ptl    = (ushort*)alloc((size_t)NPE * 2);
    ushort* ch     = (ushort*)alloc((size_t)NPE * 2);
    ushort* cl     = (ushort*)alloc((size_t)NPE * 2);
    float*  tpo    = (float*)alloc((size_t)NPE * 4);
    // pacc1 (33.5 MB) reused as corrp (16 slices = 16.8 MB);
    // pacc2 (8.4 MB) reused as corrsum (2 halves = 2 MB)
    float*  pacc1  = (float*)alloc((size_t)4 * N_NODES * HID * 4);
    float*  corrp  = pacc1;
    float*  pacc2  = (float*)alloc((size_t)4 * N_NODES * OUTD * 4);
    float*  corrsum= pacc2;
    float*  gamma  = (float*)alloc((size_t)11 * N_NODES * 4);
    float*  y      = (float*)alloc((size_t)11 * NM * 4);

    hipMemsetAsync(outdeg, 0, N_NODES * 4, stream);
    hipMemsetAsync(indeg, 0, N_NODES * 4, stream);
    hipMemsetAsync(fill, 0, N_NODES * 4, stream);

    k_degrees<<<E_EDGES / 256, 256, 0, stream>>>(src, dst, outdeg, indeg);
    k_invs<<<N_NODES / 256, 256, 0, stream>>>(outdeg, indeg, dinv, d2);
    k_scan<<<1, 64, 0, stream>>>(indeg, rp);
    k_scatter<<<E_EDGES / 256, 256, 0, stream>>>(src, dst, rp, fill, dinv, d2, col, wl, wg);

    // pack inputs for MFMA encoder GEMMs (fragment-major hi/lo bf16)
    k_split_rm<<<(N_NODES * IND / 8 + 255) / 256, 256, 0, stream>>>(
        node_feat, nfh, nfl, N_NODES * IND / 8);
    k_splitT<<<dim3(IND / 64, HID / 64), 256, 0, stream>>>(lin1_w, w1th, w1tl, IND, HID);
    k_splitT<<<dim3(HID / 64, OUTD / 64), 256, 0, stream>>>(lin2_w, w2th, w2tl, HID, OUTD);

    // x = relu(nf@W1+b1)@W2+b2 -> y slot 0   (K-split z=4, packed operands)
    k_xgemm_zp<16, 256><<<dim3(64, 8, 4), 256, 0, stream>>>(nfh, nfl, w1th, w1tl, pacc1);
    k_finzp<HID, true, true><<<(N_NODES * HID / 8) / 256, 256, 0, stream>>>(
        pacc1, lin1_b, nullptr, hh, hl);
    k_xgemm_zp<8, 128><<<dim3(64, 2, 4), 256, 0, stream>>>(hh, hl, w2th, w2tl, pacc2);
    k_finzp<OUTD, false, false><<<(N_NODES * OUTD / 8) / 256, 256, 0, stream>>>(
        pacc2, lin2_b, y, nullptr, nullptr);

    k_pe0<<<N_NODES / 64, 256, 0, stream>>>(pos_enc, pe_w, pe_b, pe, raw, pth, ptl,
                                            gate_w, gate_b, temp, gamma);

    // monomial chain: y_m = A^m x
    for (int m = 1; m <= KHOP; ++m) {
        k_spmm<<<N_NODES, 128, 0, stream>>>(y + (size_t)(m - 1) * NM,
                                            y + (size_t)m * NM, rp, col, wl);
    }

    // pe loop — collects gamma[1..10]
    for (int i = 0; i < KHOP; ++i) {
        k_cmat<<<N_NODES / 4, dim3(64, 4), 0, stream>>>(pe, cor_w, cor_b, ch, cl);
        k_corr5<<<dim3(N_NODES / 64, NCHUNK), 256, 0, stream>>>(ch, cl, pth, ptl, corrp);
        k_csum<<<dim3(NPE / 8 / 256, 2), 256, 0, stream>>>(corrp, corrsum);
        k_ahat<<<N_NODES, 64, 0, stream>>>(pe, tpo, rp, col, wg, d2);
        k_update<<<N_NODES / 64, 256, 0, stream>>>(tpo, corrsum, raw, pe, gate_w,
                                                   gate_b, temp, gamma, pth, ptl, i + 1);
    }

    k_out<<<N_NODES, 128, 0, stream>>>(y, gamma, dout);
    k_pecopy<<<(NPE + 255) / 256, 256, 0, stream>>>(pe, dout);
}